// Round 10
// baseline (41118.860 us; speedup 1.0000x reference)
//
#include <hip/hip_runtime.h>
#include <cstdint>
#include <cstddef>

#define TINYF 1.17549435e-38

__device__ __forceinline__ uint32_t rotl32(uint32_t x, int r){ return (x<<r)|(x>>(32-r)); }

// threefry2x32, 20 rounds (exact JAX schedule)
__device__ __forceinline__ void tf2x32(uint32_t k0, uint32_t k1, uint32_t x0, uint32_t x1,
                                       uint32_t& o0, uint32_t& o1){
  uint32_t k2 = k0 ^ k1 ^ 0x1BD11BDAu;
  x0 += k0; x1 += k1;
  x0 += x1; x1 = rotl32(x1,13); x1 ^= x0;
  x0 += x1; x1 = rotl32(x1,15); x1 ^= x0;
  x0 += x1; x1 = rotl32(x1,26); x1 ^= x0;
  x0 += x1; x1 = rotl32(x1, 6); x1 ^= x0;
  x0 += k1; x1 += k2 + 1u;
  x0 += x1; x1 = rotl32(x1,17); x1 ^= x0;
  x0 += x1; x1 = rotl32(x1,29); x1 ^= x0;
  x0 += x1; x1 = rotl32(x1,16); x1 ^= x0;
  x0 += x1; x1 = rotl32(x1,24); x1 ^= x0;
  x0 += k2; x1 += k0 + 2u;
  x0 += x1; x1 = rotl32(x1,13); x1 ^= x0;
  x0 += x1; x1 = rotl32(x1,15); x1 ^= x0;
  x0 += x1; x1 = rotl32(x1,26); x1 ^= x0;
  x0 += x1; x1 = rotl32(x1, 6); x1 ^= x0;
  x0 += k0; x1 += k1 + 3u;
  x0 += x1; x1 = rotl32(x1,17); x1 ^= x0;
  x0 += x1; x1 = rotl32(x1,29); x1 ^= x0;
  x0 += x1; x1 = rotl32(x1,16); x1 ^= x0;
  x0 += x1; x1 = rotl32(x1,24); x1 ^= x0;
  x0 += k1; x1 += k2 + 4u;
  x0 += x1; x1 = rotl32(x1,13); x1 ^= x0;
  x0 += x1; x1 = rotl32(x1,15); x1 ^= x0;
  x0 += x1; x1 = rotl32(x1,26); x1 ^= x0;
  x0 += x1; x1 = rotl32(x1, 6); x1 ^= x0;
  o0 = x0 + k2; o1 = x1 + k0 + 5u;
}

// Fused perm-logits GEMM (f64 accumulate) + f64 gumbel + argmax via atomicMax.
// Tile 128(bt) x 64(n); n0 = h*4096 + i*64 -> one (h,i) per block, cols = j.
// packed[bt,h,j] = max_i ( (sortable_enc_f64(logit+gumbel) & ~63) | (63-i) ).
__global__ __launch_bounds__(256) void logits_argmax(
    const float* __restrict__ A, const float* __restrict__ Bw,
    unsigned long long* __restrict__ packed){
  __shared__ float As[16][132];
  __shared__ float Bs[16][68];
  const int tid = threadIdx.x;
  const long m0 = (long)blockIdx.y * 128;
  const long n0 = (long)blockIdx.x * 64;
  const int tx = tid & 15, ty = tid >> 4;
  const int r0 = ty * 8, c0 = tx * 4;
  double acc[8][4];
#pragma unroll
  for (int i=0;i<8;i++){ acc[i][0]=0.; acc[i][1]=0.; acc[i][2]=0.; acc[i][3]=0.; }
  const int arow = tid >> 2, akq = (tid & 3) * 4;
  const int bkk = tid >> 4, bnq = (tid & 15) * 4;
#pragma unroll 1
  for (int k0=0;k0<512;k0+=16){
    {
      float4 v0 = *reinterpret_cast<const float4*>(&A[(m0+arow)*512 + k0 + akq]);
      float4 v1 = *reinterpret_cast<const float4*>(&A[(m0+arow+64)*512 + k0 + akq]);
      As[akq+0][arow] = v0.x; As[akq+1][arow] = v0.y; As[akq+2][arow] = v0.z; As[akq+3][arow] = v0.w;
      As[akq+0][arow+64] = v1.x; As[akq+1][arow+64] = v1.y; As[akq+2][arow+64] = v1.z; As[akq+3][arow+64] = v1.w;
      *reinterpret_cast<float4*>(&Bs[bkk][bnq]) =
        *reinterpret_cast<const float4*>(&Bw[(long)(k0+bkk)*32768 + n0 + bnq]);
    }
    __syncthreads();
#pragma unroll 1
    for (int kk=0;kk<16;kk++){
      float a[8], b[4];
      *reinterpret_cast<float4*>(&a[0]) = *reinterpret_cast<const float4*>(&As[kk][r0]);
      *reinterpret_cast<float4*>(&a[4]) = *reinterpret_cast<const float4*>(&As[kk][r0+4]);
      *reinterpret_cast<float4*>(&b[0]) = *reinterpret_cast<const float4*>(&Bs[kk][c0]);
#pragma unroll
      for (int i=0;i<8;i++){
        acc[i][0] = fma((double)a[i], (double)b[0], acc[i][0]);
        acc[i][1] = fma((double)a[i], (double)b[1], acc[i][1]);
        acc[i][2] = fma((double)a[i], (double)b[2], acc[i][2]);
        acc[i][3] = fma((double)a[i], (double)b[3], acc[i][3]);
      }
    }
    __syncthreads();
  }
  const int h = (int)(n0 >> 12);
  const int i = (int)((n0 >> 6) & 63);
#pragma unroll 1
  for (int ii=0; ii<8; ii++){
    const int bt = (int)(m0 + r0 + ii);
    const int b = bt >> 11, t = bt & 2047;
    const int bh = b*8 + h;
    uint32_t kk0, kk1;
    tf2x32(0u, 42u, 0u, (uint32_t)t, kk0, kk1);      // fold_in(key(42), t)
    const uint32_t nb = (uint32_t)bh*4096u + (uint32_t)i*64u + (uint32_t)c0;
    unsigned long long* dst = packed + (size_t)bt*512 + (size_t)h*64 + c0;
#pragma unroll 1
    for (int jj=0;jj<4;jj++){
      uint32_t o0, o1;
      // V3: partitionable counter scheme, 32-bit output = bits1 ^ bits2
      // (jax/_src/prng.py::_threefry_random_bits_partitionable, bit_width in [8,16,32])
      tf2x32(kk0, kk1, 0u, nb + (uint32_t)jj, o0, o1);
      uint32_t bits = o0 ^ o1;
      double f = (double)(__uint_as_float((bits>>9) | 0x3f800000u)) - 1.0;
      double u = fmax(TINYF, f * (1.0 - TINYF) + TINYF);
      double g = -log(-log(u));
      double val = acc[ii][jj] + g;
      uint64_t e = (uint64_t)__double_as_longlong(val);
      e = (e >> 63) ? ~e : (e | 0x8000000000000000ull);
      unsigned long long pv = (e & ~63ull) | (unsigned long long)(63 - i);
      atomicMax(dst + jj, pv);
    }
  }
}

__global__ __launch_bounds__(256) void idx_convert(const unsigned long long* __restrict__ packed,
                                                   unsigned char* __restrict__ idx){
  const size_t m = (size_t)blockIdx.x*2048 + (size_t)threadIdx.x*8;
#pragma unroll
  for (int e=0;e<8;e++) idx[m+e] = (unsigned char)(63u - (unsigned)(packed[m+e] & 63ull));
}

// q/k/v projections, f64 accumulate, f32 store. z: 0=q(l2),1=k(l2),2=v(silu only)
__global__ __launch_bounds__(256) void gemm_qkv(
    const float* __restrict__ A, const float* __restrict__ Wq, const float* __restrict__ Wk,
    const float* __restrict__ Wv, float* __restrict__ qb, float* __restrict__ kb,
    float* __restrict__ vb){
  const int z = blockIdx.z;
  const float* Bw = (z==0) ? Wq : ((z==1) ? Wk : Wv);
  float* C = (z==0) ? qb : ((z==1) ? kb : vb);
  __shared__ float As[16][132];
  __shared__ float Bs[16][68];
  const int tid = threadIdx.x;
  const long m0 = (long)blockIdx.y * 128;
  const long n0 = (long)blockIdx.x * 64;
  const int tx = tid & 15, ty = tid >> 4;
  const int r0 = ty * 8, c0 = tx * 4;
  double acc[8][4];
#pragma unroll
  for (int i=0;i<8;i++){ acc[i][0]=0.; acc[i][1]=0.; acc[i][2]=0.; acc[i][3]=0.; }
  const int arow = tid >> 2, akq = (tid & 3) * 4;
  const int bkk = tid >> 4, bnq = (tid & 15) * 4;
#pragma unroll 1
  for (int k0=0;k0<512;k0+=16){
    {
      float4 v0 = *reinterpret_cast<const float4*>(&A[(m0+arow)*512 + k0 + akq]);
      float4 v1 = *reinterpret_cast<const float4*>(&A[(m0+arow+64)*512 + k0 + akq]);
      As[akq+0][arow] = v0.x; As[akq+1][arow] = v0.y; As[akq+2][arow] = v0.z; As[akq+3][arow] = v0.w;
      As[akq+0][arow+64] = v1.x; As[akq+1][arow+64] = v1.y; As[akq+2][arow+64] = v1.z; As[akq+3][arow+64] = v1.w;
      *reinterpret_cast<float4*>(&Bs[bkk][bnq]) =
        *reinterpret_cast<const float4*>(&Bw[(long)(k0+bkk)*512 + n0 + bnq]);
    }
    __syncthreads();
#pragma unroll 1
    for (int kk=0;kk<16;kk++){
      float a[8], b[4];
      *reinterpret_cast<float4*>(&a[0]) = *reinterpret_cast<const float4*>(&As[kk][r0]);
      *reinterpret_cast<float4*>(&a[4]) = *reinterpret_cast<const float4*>(&As[kk][r0+4]);
      *reinterpret_cast<float4*>(&b[0]) = *reinterpret_cast<const float4*>(&Bs[kk][c0]);
#pragma unroll
      for (int i=0;i<8;i++){
        acc[i][0] = fma((double)a[i], (double)b[0], acc[i][0]);
        acc[i][1] = fma((double)a[i], (double)b[1], acc[i][1]);
        acc[i][2] = fma((double)a[i], (double)b[2], acc[i][2]);
        acc[i][3] = fma((double)a[i], (double)b[3], acc[i][3]);
      }
    }
    __syncthreads();
  }
#pragma unroll 1
  for (int i=0;i<8;i++){
#pragma unroll
    for (int j=0;j<4;j++){ double zz=acc[i][j]; acc[i][j] = zz/(1.0+exp(-zz)); }
    if (z != 2){   // q,k: per-head l2norm over the 64-col head block
      double s = acc[i][0]*acc[i][0] + acc[i][1]*acc[i][1] + acc[i][2]*acc[i][2] + acc[i][3]*acc[i][3];
      s += __shfl_xor(s,1); s += __shfl_xor(s,2); s += __shfl_xor(s,4); s += __shfl_xor(s,8);
      double sc = 1.0/(sqrt(s)+1e-6);
#pragma unroll
      for (int j=0;j<4;j++) acc[i][j]*=sc;
    }
    float4 o; o.x=(float)acc[i][0]; o.y=(float)acc[i][1]; o.z=(float)acc[i][2]; o.w=(float)acc[i][3];
    *reinterpret_cast<float4*>(&C[(m0+r0+i)*512 + n0 + c0]) = o;
  }
}

// block = 4 waves, wave w handles row r; 8 head-dots of length 512, f64 accumulate
__global__ __launch_bounds__(256) void beta_sigmoid(const float* __restrict__ x,
                                                    const float* __restrict__ Wb,
                                                    float* __restrict__ beta){
  const int w = threadIdx.x >> 6, l = threadIdx.x & 63;
  const int r = blockIdx.x*4 + w;
  double a[8];
#pragma unroll
  for (int hh=0; hh<8; hh++) a[hh]=0.;
  const float* xr = x + (size_t)r*512;
#pragma unroll 1
  for (int c=0;c<8;c++){
    double xv = (double)xr[c*64 + l];
    const float* wrow = Wb + (size_t)(c*64+l)*8;
#pragma unroll
    for (int hh=0;hh<8;hh++) a[hh] = fma(xv, (double)wrow[hh], a[hh]);
  }
#pragma unroll 1
  for (int hh=0;hh<8;hh++){
    double s = a[hh];
    s += __shfl_xor(s,1); s += __shfl_xor(s,2); s += __shfl_xor(s,4);
    s += __shfl_xor(s,8); s += __shfl_xor(s,16); s += __shfl_xor(s,32);
    if (l == hh) beta[(size_t)r*8 + hh] = (float)(1.0/(1.0+exp(-s)));
  }
}

// atomic-free recurrence, f64 state: P*M via ballot row-masks + deterministic gather.
__global__ __launch_bounds__(256) void recurrence(
    const float* __restrict__ q, const float* __restrict__ k, const float* __restrict__ v,
    const float* __restrict__ beta, const unsigned char* __restrict__ idx,
    const int* __restrict__ mask, float* __restrict__ attn){
  constexpr int MS = 66;   // doubles per padded row (132 banks, %32=4)
  const int b = blockIdx.x >> 3, h = blockIdx.x & 7;
  __shared__ double M1[64*MS];
  __shared__ double M2[64*MS];
  __shared__ double qs[64], ks[64], vs[64], dl[64];
  __shared__ double part[4][64];
  __shared__ unsigned char ids[64];
  const int tid = threadIdx.x;
  const int l6 = tid & 63, g6 = tid >> 6;
  for (int i = tid; i < 64*MS; i += 256){ M1[i] = 0.; }
  __syncthreads();
#pragma unroll 1
  for (int t=0;t<2048;t++){
    const int bt = b*2048 + t;
    const size_t base = (size_t)bt*512 + (size_t)h*64;
    if (g6==0)      qs[l6] = (double)q[base+l6];
    else if (g6==1) ks[l6] = (double)k[base+l6];
    else if (g6==2) vs[l6] = (double)v[base+l6];
    else            ids[l6] = idx[(size_t)bt*512 + h*64 + l6];
    const double bval = (double)beta[(size_t)bt*8+h] * (double)mask[bt];
    __syncthreads();
    // lane l6 owns output row l6: mask of source rows j with ids[j]==l6
    const unsigned char myid = ids[l6];
    uint64_t mymask = 0;
#pragma unroll 1
    for (int i=0;i<64;i++){
      uint64_t bal = __ballot(myid == (unsigned char)i);
      if (l6 == i) mymask = bal;
    }
    double acc[16];
#pragma unroll
    for (int d=0;d<16;d++) acc[d]=0.;
    uint64_t mm = mymask;
    const int dbase = g6*16;
#pragma unroll 1
    while (mm){
      const int j = __builtin_ctzll(mm); mm &= (mm-1);
      const double* src = &M1[j*MS + dbase];
#pragma unroll
      for (int d=0;d<16;d+=2){
        double2 vv = *reinterpret_cast<const double2*>(&src[d]);
        acc[d]+=vv.x; acc[d+1]+=vv.y;
      }
    }
#pragma unroll
    for (int d=0;d<16;d+=2){
      double2 st; st.x = acc[d]; st.y = acc[d+1];
      *reinterpret_cast<double2*>(&M2[l6*MS + dbase + d]) = st;
    }
    __syncthreads();
    // out[d] = sum_r qs[r]*M2[r][d] ; delta[j] = vs[j] - sum_d M2[j][d]*ks[d]
    {
      double accO = 0.;
#pragma unroll
      for (int hh=0; hh<16; hh++){
        const int r = g6*16 + hh;
        accO = fma(qs[r], M2[r*MS + l6], accO);
      }
      part[g6][l6] = accO;
      const int j = tid >> 2, qd = tid & 3;
      double accK = 0.;
#pragma unroll
      for (int dd=0; dd<16; dd++){
        const int d2 = qd*16 + dd;
        accK = fma(M2[j*MS + d2], ks[d2], accK);
      }
      accK += __shfl_xor(accK,1); accK += __shfl_xor(accK,2);
      if (qd==0) dl[j] = vs[j] - accK;
    }
    __syncthreads();
    if (tid < 64) attn[base + tid] = (float)(part[0][tid]+part[1][tid]+part[2][tid]+part[3][tid]);
    // M1 = M2 + bval*ks[row]*dl[col]
    {
      const int i = tid >> 2, cq = (tid & 3)*16;
      const double bk = bval * ks[i];
#pragma unroll
      for (int c2=0;c2<16;c2+=2){
        double2 m2v = *reinterpret_cast<const double2*>(&M2[i*MS + cq + c2]);
        double2 dv  = *reinterpret_cast<const double2*>(&dl[cq + c2]);
        double2 r;
        r.x = fma(bk, dv.x, m2v.x); r.y = fma(bk, dv.y, m2v.y);
        *reinterpret_cast<double2*>(&M1[i*MS + cq + c2]) = r;
      }
    }
    __syncthreads();
  }
}

// Wo GEMM with fused RMS-norm, f64 accumulate: ssum during A staging, rms_w folded
// into As, 1/rms applied in epilogue ( (x/rms*w)@Wo == ((x*w)@Wo)/rms per row ).
__global__ __launch_bounds__(256) void gemm_rms(
    const float* __restrict__ A, const float* __restrict__ rw,
    const float* __restrict__ Bw, float* __restrict__ C){
  __shared__ float As[16][132];
  __shared__ float Bs[16][68];
  __shared__ double scl[128];
  const int tid = threadIdx.x;
  const long m0 = (long)blockIdx.y * 128;
  const long n0 = (long)blockIdx.x * 64;
  const int tx = tid & 15, ty = tid >> 4;
  const int r0 = ty * 8, c0 = tx * 4;
  double acc[8][4];
#pragma unroll
  for (int i=0;i<8;i++){ acc[i][0]=0.; acc[i][1]=0.; acc[i][2]=0.; acc[i][3]=0.; }
  const int arow = tid >> 2, akq = (tid & 3) * 4;
  const int bkk = tid >> 4, bnq = (tid & 15) * 4;
  double ss0 = 0., ss1 = 0.;
#pragma unroll 1
  for (int k0=0;k0<512;k0+=16){
    {
      float4 v0 = *reinterpret_cast<const float4*>(&A[(m0+arow)*512 + k0 + akq]);
      float4 v1 = *reinterpret_cast<const float4*>(&A[(m0+arow+64)*512 + k0 + akq]);
      float4 w4 = *reinterpret_cast<const float4*>(&rw[k0 + akq]);
      ss0 += (double)v0.x*v0.x + (double)v0.y*v0.y + (double)v0.z*v0.z + (double)v0.w*v0.w;
      ss1 += (double)v1.x*v1.x + (double)v1.y*v1.y + (double)v1.z*v1.z + (double)v1.w*v1.w;
      As[akq+0][arow] = v0.x*w4.x; As[akq+1][arow] = v0.y*w4.y;
      As[akq+2][arow] = v0.z*w4.z; As[akq+3][arow] = v0.w*w4.w;
      As[akq+0][arow+64] = v1.x*w4.x; As[akq+1][arow+64] = v1.y*w4.y;
      As[akq+2][arow+64] = v1.z*w4.z; As[akq+3][arow+64] = v1.w*w4.w;
      *reinterpret_cast<float4*>(&Bs[bkk][bnq]) =
        *reinterpret_cast<const float4*>(&Bw[(long)(k0+bkk)*512 + n0 + bnq]);
    }
    __syncthreads();
#pragma unroll 1
    for (int kk=0;kk<16;kk++){
      float a[8], b[4];
      *reinterpret_cast<float4*>(&a[0]) = *reinterpret_cast<const float4*>(&As[kk][r0]);
      *reinterpret_cast<float4*>(&a[4]) = *reinterpret_cast<const float4*>(&As[kk][r0+4]);
      *reinterpret_cast<float4*>(&b[0]) = *reinterpret_cast<const float4*>(&Bs[kk][c0]);
#pragma unroll
      for (int i=0;i<8;i++){
        acc[i][0] = fma((double)a[i], (double)b[0], acc[i][0]);
        acc[i][1] = fma((double)a[i], (double)b[1], acc[i][1]);
        acc[i][2] = fma((double)a[i], (double)b[2], acc[i][2]);
        acc[i][3] = fma((double)a[i], (double)b[3], acc[i][3]);
      }
    }
    __syncthreads();
  }
  ss0 += __shfl_xor(ss0,1); ss0 += __shfl_xor(ss0,2);
  ss1 += __shfl_xor(ss1,1); ss1 += __shfl_xor(ss1,2);
  if ((tid & 3) == 0){
    scl[arow]    = 1.0/sqrt(ss0*(1.0/512.0) + 1e-6);
    scl[arow+64] = 1.0/sqrt(ss1*(1.0/512.0) + 1e-6);
  }
  __syncthreads();
#pragma unroll 1
  for (int i=0;i<8;i++){
    const double sc = scl[r0+i];
    float4 o;
    o.x=(float)(acc[i][0]*sc); o.y=(float)(acc[i][1]*sc);
    o.z=(float)(acc[i][2]*sc); o.w=(float)(acc[i][3]*sc);
    *reinterpret_cast<float4*>(&C[(m0+r0+i)*512 + n0 + c0]) = o;
  }
}

extern "C" void kernel_launch(void* const* d_in, const int* in_sizes, int n_in,
                              void* d_out, int out_size, void* d_ws, size_t ws_size,
                              hipStream_t stream){
  const float* x     = (const float*)d_in[0];
  const float* Wq    = (const float*)d_in[1];
  const float* Wk    = (const float*)d_in[2];
  const float* Wv    = (const float*)d_in[3];
  const float* Wo    = (const float*)d_in[4];
  const float* Wbeta = (const float*)d_in[5];
  const float* Wperm = (const float*)d_in[6];
  const float* rmsw  = (const float*)d_in[7];
  const int*   mask  = (const int*)d_in[8];
  float* out = (float*)d_out;

  char* ws = (char*)d_ws;
  const size_t QB    = 33554432ull;    // 16384*512*4 bytes
  const size_t BETAB = 524288ull;      // 16384*8*4
  // layout (109.6 MB, round-1-proven bound): kb | vb | qb | betab | idxb
  // packed (u64, 64 MB) overlays kb|vb; dead before k/v are written.
  float* kb    = (float*)ws;
  float* vb    = (float*)(ws + QB);
  float* qb    = (float*)(ws + 2*QB);
  float* betab = (float*)(ws + 3*QB);
  unsigned char* idxb = (unsigned char*)(ws + 3*QB + BETAB);
  unsigned long long* packed = (unsigned long long*)ws;

  dim3 blk(256);
  // 1) init argmax cells (enc 0 < enc(-inf))
  hipMemsetAsync(packed, 0, 16384ull*512*8, stream);
  // 2) fused f64 perm-logits GEMM + f64 gumbel + atomicMax argmax (V3 PRNG: o0^o1)
  logits_argmax<<<dim3(512,128),blk,0,stream>>>(x, Wperm, packed);
  // 3) extract idx bytes (frees packed region)
  idx_convert<<<4096,blk,0,stream>>>(packed, idxb);
  // 4) q/k/v projections (one dispatch), 5) beta
  gemm_qkv<<<dim3(8,128,3),blk,0,stream>>>(x, Wq, Wk, Wv, qb, kb, vb);
  beta_sigmoid<<<4096,blk,0,stream>>>(x, Wbeta, betab);
  // 6) f64 sequential delta-rule recurrence, q->attn in place in qb
  recurrence<<<64,blk,0,stream>>>(qb, kb, vb, betab, idxb, mask, qb);
  // 7) fused f64 RMS-norm + Wo projection -> d_out
  gemm_rms<<<dim3(8,128),blk,0,stream>>>(qb, rmsw, Wo, out);
}